// Round 13
// baseline (346.190 us; speedup 1.0000x reference)
//
#include <hip/hip_runtime.h>
#include <math.h>

// Problem constants
#define Bb 4
#define Ll 2048
#define Ee 512
#define NH 8
#define HD 64
#define LOG2E 1.44269504f

typedef __attribute__((ext_vector_type(8))) short bf16x8;   // 8 bf16 = 4 VGPR
typedef __attribute__((ext_vector_type(4))) short bf16x4;   // 8 bytes
typedef __attribute__((ext_vector_type(4))) float f32x4;

#define MFMA16(a, b, c) __builtin_amdgcn_mfma_f32_16x16x32_bf16(a, b, c, 0, 0, 0)

// Split fp32 into bf16 hi + bf16 lo (RNE both). x ≈ hi + lo with ~2^-17 rel err.
__device__ inline void split_bf16(float x, short& hi, short& lo) {
    unsigned u = __float_as_uint(x);
    unsigned r = (u + 0x7fffu + ((u >> 16) & 1u)) & 0xffff0000u;
    hi = (short)(r >> 16);
    float rem = x - __uint_as_float(r);
    unsigned u2 = __float_as_uint(rem);
    unsigned r2 = u2 + 0x7fffu + ((u2 >> 16) & 1u);
    lo = (short)(r2 >> 16);
}

// ---------------------------------------------------------------------------
// split_x: x fp32 [M=8192][K=512] -> xsh/xsl bf16, k pre-swizzled per 64-group
// ---------------------------------------------------------------------------
__global__ __launch_bounds__(256) void split_x_kernel(
    const float* __restrict__ x, short* __restrict__ xsh, short* __restrict__ xsl)
{
    const size_t base = ((size_t)blockIdx.x * 256 + threadIdx.x) * 8;
    const int m = (int)(base >> 9);
    const int k = (int)(base & 511);
    const int c  = (k >> 3) & 7;
    const int g  = k & ~63;
    const int cs = c ^ (m & 7);
    float4 v0 = *(const float4*)(x + base);
    float4 v1 = *(const float4*)(x + base + 4);
    float f[8] = {v0.x, v0.y, v0.z, v0.w, v1.x, v1.y, v1.z, v1.w};
    bf16x8 hv, lv;
    #pragma unroll
    for (int i = 0; i < 8; ++i) {
        short th, tl;
        split_bf16(f[i], th, tl);
        hv[i] = th;
        lv[i] = tl;
    }
    const size_t dst = (size_t)m * 512 + g + (cs << 3);
    *(bf16x8*)(xsh + dst) = hv;
    *(bf16x8*)(xsl + dst) = lv;
}

// ---------------------------------------------------------------------------
// split_w: W fp32 [K][N] (z in {q,k,v}) -> wth/wtl bf16 transposed [z][n][k],
// k pre-swizzled per 64-group: chunk c -> c ^ (n&7).
// ---------------------------------------------------------------------------
__global__ __launch_bounds__(256) void split_w_kernel(
    const float* __restrict__ Wq, const float* __restrict__ Wk,
    const float* __restrict__ Wv, short* __restrict__ wth, short* __restrict__ wtl)
{
    __shared__ float lds[64][65];
    const float* W = (blockIdx.z == 0) ? Wq : (blockIdx.z == 1) ? Wk : Wv;
    const int k0 = blockIdx.x * 64;
    const int n0 = blockIdx.y * 64;
    const int t  = threadIdx.x;

    #pragma unroll
    for (int it = 0; it < 16; ++it) {
        int lin = it * 256 + t;
        int kk = lin >> 6, nn = lin & 63;
        lds[kk][nn] = W[(size_t)(k0 + kk) * Ee + n0 + nn];
    }
    __syncthreads();

    #pragma unroll
    for (int it = 0; it < 2; ++it) {
        int task = it * 256 + t;
        int nn = task >> 3;
        int c  = task & 7;
        int n  = n0 + nn;
        int cs = c ^ (n & 7);
        bf16x8 hv, lv;
        #pragma unroll
        for (int i = 0; i < 8; ++i) {
            short th, tl;
            split_bf16(lds[c * 8 + i][nn], th, tl);
            hv[i] = th;
            lv[i] = tl;
        }
        size_t dst = (size_t)blockIdx.z * Ee * Ee + (size_t)n * 512 + k0 + (cs << 3);
        *(bf16x8*)(wth + dst) = hv;
        *(bf16x8*)(wtl + dst) = lv;
    }
}

// ---------------------------------------------------------------------------
// QKV projection via split-bf16 MFMA (verified r10). One change: Q outputs
// (z==0) scaled by log2(e) so attn softmax uses raw exp2 (saves a v_mul per
// exp; mathematically identical).
// ---------------------------------------------------------------------------
__global__ __launch_bounds__(256) void qkv_mfma_kernel(
    const short* __restrict__ xsh, const short* __restrict__ xsl,
    const short* __restrict__ wth, const short* __restrict__ wtl,
    const float* __restrict__ bq, const float* __restrict__ bk,
    const float* __restrict__ bvec,
    short* __restrict__ Qhi, short* __restrict__ Qlo,
    short* __restrict__ Khi, short* __restrict__ Klo,
    short* __restrict__ Vthi, short* __restrict__ Vtlo)
{
    __shared__ short axh[4096], axl[4096], awh[4096], awl[4096];
    __shared__ float ost[64][65];

    const int t    = threadIdx.x;
    const int ln   = t & 63;
    const int w    = t >> 6;
    const int lo16 = ln & 15;
    const int hi4  = ln >> 4;
    const int n0 = blockIdx.x * 64;
    const int m0 = blockIdx.y * 64;
    const int z  = blockIdx.z;

    const float* bias = (z == 0) ? bq : (z == 1) ? bk : bvec;
    const short* wsh = wth + (size_t)z * Ee * Ee;
    const short* wsl = wtl + (size_t)z * Ee * Ee;

    f32x4 o[4];
    #pragma unroll
    for (int i = 0; i < 4; ++i) o[i] = (f32x4){0.f, 0.f, 0.f, 0.f};

    for (int k0 = 0; k0 < Ee; k0 += 64) {
        __syncthreads();
        const short* src;
        short* dst;
        if (w == 0)      { src = xsh + (size_t)m0 * 512 + k0; dst = axh; }
        else if (w == 1) { src = xsl + (size_t)m0 * 512 + k0; dst = axl; }
        else if (w == 2) { src = wsh + (size_t)n0 * 512 + k0; dst = awh; }
        else             { src = wsl + (size_t)n0 * 512 + k0; dst = awl; }
        #pragma unroll
        for (int it = 0; it < 8; ++it) {
            int row = it * 8 + (ln >> 3);
            *(bf16x8*)(dst + row * 64 + (ln & 7) * 8) =
                *(const bf16x8*)(src + (size_t)row * 512 + (ln & 7) * 8);
        }
        __syncthreads();

        #pragma unroll
        for (int kc = 0; kc < 2; ++kc) {
            int arow = w * 16 + lo16;
            int ac   = (kc * 4 + hi4) ^ (arow & 7);
            bf16x8 ah = *(const bf16x8*)(axh + arow * 64 + (ac << 3));
            bf16x8 al = *(const bf16x8*)(axl + arow * 64 + (ac << 3));
            #pragma unroll
            for (int nt = 0; nt < 4; ++nt) {
                int brow = nt * 16 + lo16;
                int bc   = (kc * 4 + hi4) ^ (brow & 7);
                bf16x8 bh = *(const bf16x8*)(awh + brow * 64 + (bc << 3));
                bf16x8 bl = *(const bf16x8*)(awl + brow * 64 + (bc << 3));
                o[nt] = MFMA16(ah, bh, o[nt]);
                o[nt] = MFMA16(ah, bl, o[nt]);
                o[nt] = MFMA16(al, bh, o[nt]);
            }
        }
    }

    #pragma unroll
    for (int nt = 0; nt < 4; ++nt)
        #pragma unroll
        for (int r = 0; r < 4; ++r)
            ost[w * 16 + hi4 * 4 + r][nt * 16 + lo16] = o[nt][r];
    __syncthreads();

    const int tx = t & 15;
    const int ty = t >> 4;
    const int b  = m0 >> 11;
    const int l0 = m0 & 2047;
    const int h  = blockIdx.x;

    if (z < 2) {
        const float sc = (z == 0) ? LOG2E : 1.0f;   // Q pre-scaled for exp2 softmax
        const float4 bv4 = *reinterpret_cast<const float4*>(&bias[n0 + tx * 4]);
        #pragma unroll
        for (int i = 0; i < 4; ++i) {
            int l = l0 + ty * 4 + i;
            size_t rowbase = ((size_t)(b * NH + h) * Ll + l) * (size_t)HD;
            float f[4];
            f[0] = (ost[ty * 4 + i][tx * 4 + 0] + bv4.x) * sc;
            f[1] = (ost[ty * 4 + i][tx * 4 + 1] + bv4.y) * sc;
            f[2] = (ost[ty * 4 + i][tx * 4 + 2] + bv4.z) * sc;
            f[3] = (ost[ty * 4 + i][tx * 4 + 3] + bv4.w) * sc;
            bf16x4 hv, lv;
            #pragma unroll
            for (int j = 0; j < 4; ++j) {
                short th, tl;
                split_bf16(f[j], th, tl);
                hv[j] = th;
                lv[j] = tl;
            }
            if (z == 0) {
                *(bf16x4*)(Qhi + rowbase + tx * 4) = hv;
                *(bf16x4*)(Qlo + rowbase + tx * 4) = lv;
            } else {
                int dpos = (((tx >> 1) ^ (l & 7)) << 3) + ((tx & 1) << 2);
                *(bf16x4*)(Khi + rowbase + dpos) = hv;
                *(bf16x4*)(Klo + rowbase + dpos) = lv;
            }
        }
    } else {
        #pragma unroll
        for (int it = 0; it < 16; ++it) {
            int lin = it * 256 + t;
            int d = lin >> 6, lloc = lin & 63;
            float f = ost[lloc][d] + bias[n0 + d];
            short hi, lo2;
            split_bf16(f, hi, lo2);
            int colp = ((((lloc >> 3) ^ (d & 7)) << 3) | (lloc & 7));
            size_t idx = ((size_t)(b * NH + h) * HD + d) * (size_t)Ll + l0 + colp;
            Vthi[idx] = hi;
            Vtlo[idx] = lo2;
        }
    }
}

// ---------------------------------------------------------------------------
// FALLBACK QKV (fp32 vector GEMM) — only if ws_size too small. Same Q-scaling.
// ---------------------------------------------------------------------------
__global__ __launch_bounds__(256) void qkv_gemm_kernel(
    const float* __restrict__ x,
    const float* __restrict__ Wq, const float* __restrict__ bq,
    const float* __restrict__ Wk, const float* __restrict__ bk,
    const float* __restrict__ Wv, const float* __restrict__ bv,
    short* __restrict__ Qhi, short* __restrict__ Qlo,
    short* __restrict__ Khi, short* __restrict__ Klo,
    short* __restrict__ Vthi, short* __restrict__ Vtlo)
{
    const float* W; const float* bias;
    if (blockIdx.z == 0)      { W = Wq; bias = bq; }
    else if (blockIdx.z == 1) { W = Wk; bias = bk; }
    else                      { W = Wv; bias = bv; }

    __shared__ float xs[16][65];
    __shared__ float ws[16][65];
    __shared__ float tr[64][65];

    const int t  = threadIdx.x;
    const int tx = t & 15;
    const int ty = t >> 4;
    const int m0 = blockIdx.y * 64;
    const int n0 = blockIdx.x * 64;
    const int h  = blockIdx.x;

    float acc[4][4] = {};

    for (int k0 = 0; k0 < Ee; k0 += 16) {
        __syncthreads();
        #pragma unroll
        for (int it = 0; it < 4; ++it) {
            int lin = it * 256 + t;
            int mm = lin >> 4, kk = lin & 15;
            xs[kk][mm] = x[(size_t)(m0 + mm) * Ee + (k0 + kk)];
            int kk2 = lin >> 6, c = lin & 63;
            ws[kk2][c] = W[(size_t)(k0 + kk2) * Ee + (n0 + c)];
        }
        __syncthreads();
        #pragma unroll
        for (int kk = 0; kk < 16; ++kk) {
            float a[4], b[4];
            #pragma unroll
            for (int i = 0; i < 4; ++i) a[i] = xs[kk][ty * 4 + i];
            #pragma unroll
            for (int j = 0; j < 4; ++j) b[j] = ws[kk][tx * 4 + j];
            #pragma unroll
            for (int i = 0; i < 4; ++i)
                #pragma unroll
                for (int j = 0; j < 4; ++j)
                    acc[i][j] = fmaf(a[i], b[j], acc[i][j]);
        }
    }

    const float4 bv4 = *reinterpret_cast<const float4*>(&bias[n0 + tx * 4]);
    const int z = blockIdx.z;
    const int b = m0 >> 11;
    const int l0 = m0 & 2047;

    if (z < 2) {
        const float sc = (z == 0) ? LOG2E : 1.0f;
        #pragma unroll
        for (int i = 0; i < 4; ++i) {
            int l = l0 + ty * 4 + i;
            size_t rowbase = ((size_t)(b * NH + h) * Ll + l) * (size_t)HD;
            float f[4];
            f[0] = (acc[i][0] + bv4.x) * sc;
            f[1] = (acc[i][1] + bv4.y) * sc;
            f[2] = (acc[i][2] + bv4.z) * sc;
            f[3] = (acc[i][3] + bv4.w) * sc;
            bf16x4 hv, lv;
            #pragma unroll
            for (int j = 0; j < 4; ++j) {
                short th, tl;
                split_bf16(f[j], th, tl);
                hv[j] = th;
                lv[j] = tl;
            }
            if (z == 0) {
                *(bf16x4*)(Qhi + rowbase + tx * 4) = hv;
                *(bf16x4*)(Qlo + rowbase + tx * 4) = lv;
            } else {
                int dpos = (((tx >> 1) ^ (l & 7)) << 3) + ((tx & 1) << 2);
                *(bf16x4*)(Khi + rowbase + dpos) = hv;
                *(bf16x4*)(Klo + rowbase + dpos) = lv;
            }
        }
    } else {
        #pragma unroll
        for (int i = 0; i < 4; ++i) {
            tr[ty * 4 + i][tx * 4 + 0] = acc[i][0] + bv4.x;
            tr[ty * 4 + i][tx * 4 + 1] = acc[i][1] + bv4.y;
            tr[ty * 4 + i][tx * 4 + 2] = acc[i][2] + bv4.z;
            tr[ty * 4 + i][tx * 4 + 3] = acc[i][3] + bv4.w;
        }
        __syncthreads();
        #pragma unroll
        for (int it = 0; it < 16; ++it) {
            int lin = it * 256 + t;
            int d = lin >> 6, lloc = lin & 63;
            float f = tr[lloc][d];
            short hi, lo2;
            split_bf16(f, hi, lo2);
            int colp = ((((lloc >> 3) ^ (d & 7)) << 3) | (lloc & 7));
            size_t idx = ((size_t)(b * NH + h) * HD + d) * (size_t)Ll + l0 + colp;
            Vthi[idx] = hi;
            Vtlo[idx] = lo2;
        }
    }
}

// ---------------------------------------------------------------------------
// Flash attention: T14 dbuf (verified r12) + NEW: 2 q-row-sets per wave
// (128-row blocks). Every K/V LDS read and the whole stage+barrier cost is
// shared across both sets (DS-reads-per-MFMA halved); QK-B MFMAs interleave
// with softmax-A VALU (independent). Softmax in exp2 domain (Q pre-scaled).
// P LDS buffer reused A-then-B (same-wave DS ordering). Grid 512 = exactly
// 2 blocks/CU, no tail. LDS 80KB unchanged.
// ---------------------------------------------------------------------------
__device__ inline void stage_ld(const short* __restrict__ Khi, const short* __restrict__ Klo,
                                const short* __restrict__ Vthi, const short* __restrict__ Vtlo,
                                int bh, int kt, int w, int ln, bf16x8* sr) {
    if (w < 2) {
        const short* src = (w == 0 ? Khi : Klo) + ((size_t)bh * Ll + kt) * (size_t)HD;
        #pragma unroll
        for (int it = 0; it < 8; ++it)
            sr[it] = *(const bf16x8*)(src + it * 512 + ln * 8);
    } else {
        const short* src0 = (w == 2 ? Vthi : Vtlo) + (size_t)bh * HD * Ll + kt;
        #pragma unroll
        for (int it = 0; it < 8; ++it) {
            int row = it * 8 + (ln >> 3);
            sr[it] = *(const bf16x8*)(src0 + (size_t)row * Ll + (ln & 7) * 8);
        }
    }
}

__global__ __launch_bounds__(256, 2) void attn_kernel(
    const short* __restrict__ Qhi, const short* __restrict__ Qlo,
    const short* __restrict__ Khi, const short* __restrict__ Klo,
    const short* __restrict__ Vthi, const short* __restrict__ Vtlo,
    float* __restrict__ out)
{
    __shared__ short ksh[2][4096], ksl[2][4096], vsh[2][4096], vsl[2][4096];
    __shared__ short psh[4][1024], psl[4][1024];

    const int t    = threadIdx.x;
    const int ln   = t & 63;
    const int w    = t >> 6;
    const int lo16 = ln & 15;
    const int hi4  = ln >> 4;
    const int q0   = blockIdx.x * 128;
    const int h    = blockIdx.y;
    const int b    = blockIdx.z;
    const int bh   = b * NH + h;

    // two q-row sets per wave: A = q0+w*32+[0,16), B = +16
    const size_t qbaseA = ((size_t)bh * Ll + q0 + w * 32 + lo16) * (size_t)HD;
    const size_t qbaseB = qbaseA + (size_t)16 * HD;
    bf16x8 qhA[2], qlA[2], qhB[2], qlB[2];
    qhA[0] = *(const bf16x8*)(Qhi + qbaseA + hi4 * 8);
    qhA[1] = *(const bf16x8*)(Qhi + qbaseA + 32 + hi4 * 8);
    qlA[0] = *(const bf16x8*)(Qlo + qbaseA + hi4 * 8);
    qlA[1] = *(const bf16x8*)(Qlo + qbaseA + 32 + hi4 * 8);
    qhB[0] = *(const bf16x8*)(Qhi + qbaseB + hi4 * 8);
    qhB[1] = *(const bf16x8*)(Qhi + qbaseB + 32 + hi4 * 8);
    qlB[0] = *(const bf16x8*)(Qlo + qbaseB + hi4 * 8);
    qlB[1] = *(const bf16x8*)(Qlo + qbaseB + 32 + hi4 * 8);

    f32x4 oA[4], oB[4];
    float mA[4], lA[4], mB[4], lB[4];
    #pragma unroll
    for (int i = 0; i < 4; ++i) {
        oA[i] = (f32x4){0.f, 0.f, 0.f, 0.f};
        oB[i] = (f32x4){0.f, 0.f, 0.f, 0.f};
        mA[i] = -INFINITY; lA[i] = 0.f;
        mB[i] = -INFINITY; lB[i] = 0.f;
    }

    bf16x8 sr[8];

    // prologue: stage tile 0 into buffer 0
    stage_ld(Khi, Klo, Vthi, Vtlo, bh, 0, w, ln, sr);
    {
        short* dst = (w == 0) ? ksh[0] : (w == 1) ? ksl[0] : (w == 2) ? vsh[0] : vsl[0];
        #pragma unroll
        for (int it = 0; it < 8; ++it)
            *(bf16x8*)(dst + it * 512 + ln * 8) = sr[it];
    }
    __syncthreads();

    int cur = 0;
    for (int i = 0; i < Ll / 64; ++i) {
        if (i < Ll / 64 - 1)
            stage_ld(Khi, Klo, Vthi, Vtlo, bh, (i + 1) * 64, w, ln, sr);

        const short* kshc = ksh[cur];
        const short* kslc = ksl[cur];
        const short* vshc = vsh[cur];
        const short* vslc = vsl[cur];

        // S = Q K^T for both sets; each K fragment read feeds 6 MFMAs
        f32x4 sA[4], sB[4];
        #pragma unroll
        for (int ct = 0; ct < 4; ++ct) {
            sA[ct] = (f32x4){0.f, 0.f, 0.f, 0.f};
            sB[ct] = (f32x4){0.f, 0.f, 0.f, 0.f};
            #pragma unroll
            for (int kc = 0; kc < 2; ++kc) {
                int key = ct * 16 + lo16;
                int c   = kc * 4 + hi4;
                int idx = key * 64 + ((c ^ (key & 7)) << 3);
                bf16x8 kbh = *(const bf16x8*)(kshc + idx);
                bf16x8 kbl = *(const bf16x8*)(kslc + idx);
                sA[ct] = MFMA16(qhA[kc], kbh, sA[ct]);
                sA[ct] = MFMA16(qhA[kc], kbl, sA[ct]);
                sA[ct] = MFMA16(qlA[kc], kbh, sA[ct]);
                sB[ct] = MFMA16(qhB[kc], kbh, sB[ct]);
                sB[ct] = MFMA16(qhB[kc], kbl, sB[ct]);
                sB[ct] = MFMA16(qlB[kc], kbh, sB[ct]);
            }
        }

        // online softmax (exp2 domain), set A
        #pragma unroll
        for (int r = 0; r < 4; ++r) {
            float mx = fmaxf(fmaxf(sA[0][r], sA[1][r]), fmaxf(sA[2][r], sA[3][r]));
            mx = fmaxf(mx, __shfl_xor(mx, 1, 64));
            mx = fmaxf(mx, __shfl_xor(mx, 2, 64));
            mx = fmaxf(mx, __shfl_xor(mx, 4, 64));
            mx = fmaxf(mx, __shfl_xor(mx, 8, 64));
            float mn = fmaxf(mA[r], mx);
            float f  = exp2f(mA[r] - mn);
            lA[r] *= f;
            #pragma unroll
            for (int nt = 0; nt < 4; ++nt) oA[nt][r] *= f;
            float su = 0.f;
            #pragma unroll
            for (int ct = 0; ct < 4; ++ct) {
                float p = exp2f(sA[ct][r] - mn);
                sA[ct][r] = p;
                su += p;
            }
            su += __shfl_xor(su, 1, 64);
            su += __shfl_xor(su, 2, 64);
            su += __shfl_xor(su, 4, 64);
            su += __shfl_xor(su, 8, 64);
            lA[r] += su;
            mA[r] = mn;
        }
        // set B
        #pragma unroll
        for (int r = 0; r < 4; ++r) {
            float mx = fmaxf(fmaxf(sB[0][r], sB[1][r]), fmaxf(sB[2][r], sB[3][r]));
            mx = fmaxf(mx, __shfl_xor(mx, 1, 64));
            mx = fmaxf(mx, __shfl_xor(mx, 2, 64));
            mx = fmaxf(mx, __shfl_xor(mx, 4, 64));
            mx = fmaxf(mx, __shfl_xor(mx, 8, 64));
            float mn = fmaxf(mB[r], mx);
            float f  = exp2f(mB[r] - mn);
            lB[r] *= f;
            #pragma unroll
            for (int nt = 0; nt < 4; ++nt) oB[nt][r] *= f;
            float su = 0.f;
            #pragma unroll
            for (int ct = 0; ct < 4; ++ct) {
                float p = exp2f(sB[ct][r] - mn);
                sB[ct][r] = p;
                su += p;
            }
            su += __shfl_xor(su, 1, 64);
            su += __shfl_xor(su, 2, 64);
            su += __shfl_xor(su, 4, 64);
            su += __shfl_xor(su, 8, 64);
            lB[r] += su;
            mB[r] = mn;
        }

        short* ph = &psh[w][0];
        short* pl = &psl[w][0];
        bf16x8 pahA[2], palA[2], pahB[2], palB[2];

        // P-A through per-wave LDS (swizzled transpose), then A-frags
        #pragma unroll
        for (int ct = 0; ct < 4; ++ct)
            #pragma unroll
            for (int r = 0; r < 4; ++r) {
                int qr    = hi4 * 4 + r;
                int chunk = (ct * 2 + (lo16 >> 3)) ^ (qr & 7);
                int idx   = qr * 64 + (chunk << 3) + (ln & 7);
                short hi, lo2;
                split_bf16(sA[ct][r], hi, lo2);
                ph[idx] = hi;
                pl[idx] = lo2;
            }
        #pragma unroll
        for (int kc = 0; kc < 2; ++kc) {
            int c   = (kc * 4 + hi4) ^ (lo16 & 7);
            int idx = lo16 * 64 + (c << 3);
            pahA[kc] = *(const bf16x8*)(ph + idx);
            palA[kc] = *(const bf16x8*)(pl + idx);
        }
        // P-B reuses the same buffer (same-wave DS ordering keeps it safe)
        #pragma unroll
        for (int ct = 0; ct < 4; ++ct)
            #pragma unroll
            for (int r = 0; r < 4; ++r) {
                int qr    = hi4 * 4 + r;
                int chunk = (ct * 2 + (lo16 >> 3)) ^ (qr & 7);
                int idx   = qr * 64 + (chunk << 3) + (ln & 7);
                short hi, lo2;
                split_bf16(sB[ct][r], hi, lo2);
                ph[idx] = hi;
                pl[idx] = lo2;
            }
        #pragma unroll
        for (int kc = 0; kc < 2; ++kc) {
            int c   = (kc * 4 + hi4) ^ (lo16 & 7);
            int idx = lo16 * 64 + (c << 3);
            pahB[kc] = *(const bf16x8*)(ph + idx);
            palB[kc] = *(const bf16x8*)(pl + idx);
        }

        // O += P V for both sets; each V fragment read feeds 6 MFMAs
        #pragma unroll
        for (int nt = 0; nt < 4; ++nt) {
            #pragma unroll
            for (int kc = 0; kc < 2; ++kc) {
                int row = nt * 16 + lo16;
                int c   = kc * 4 + hi4;
                int idx = row * 64 + ((c ^ (row & 7)) << 3);
                bf16x8 vbh = *(const bf16x8*)(vshc + idx);
                bf16x8 vbl = *(const bf16x8*)(vslc + idx);
                oA[nt] = MFMA16(pahA[kc], vbh, oA[nt]);
                oA[nt] = MFMA16(pahA[kc], vbl, oA[nt]);
                oA[nt] = MFMA16(palA[kc], vbh, oA[nt]);
                oB[nt] = MFMA16(pahB[kc], vbh, oB[nt]);
                oB[nt] = MFMA16(pahB[kc], vbl, oB[nt]);
                oB[nt] = MFMA16(palB[kc], vbh, oB[nt]);
            }
        }

        if (i < Ll / 64 - 1) {
            short* dst = (w == 0) ? ksh[cur ^ 1] : (w == 1) ? ksl[cur ^ 1]
                       : (w == 2) ? vsh[cur ^ 1] : vsl[cur ^ 1];
            #pragma unroll
            for (int it = 0; it < 8; ++it)
                *(bf16x8*)(dst + it * 512 + ln * 8) = sr[it];
        }
        __syncthreads();
        cur ^= 1;
    }

    // epilogue: both sets
    const size_t obase = ((size_t)b * Ll) * Ee + (size_t)h * HD;
    #pragma unroll
    for (int r = 0; r < 4; ++r) {
        float invA = 1.0f / lA[r];
        float invB = 1.0f / lB[r];
        int qrA = q0 + w * 32 + hi4 * 4 + r;
        int qrB = qrA + 16;
        #pragma unroll
        for (int nt = 0; nt < 4; ++nt) {
            out[obase + (size_t)qrA * Ee + nt * 16 + lo16] = oA[nt][r] * invA;
            out[obase + (size_t)qrB * Ee + nt * 16 + lo16] = oB[nt][r] * invB;
        }
    }
}

extern "C" void kernel_launch(void* const* d_in, const int* in_sizes, int n_in,
                              void* d_out, int out_size, void* d_ws, size_t ws_size,
                              hipStream_t stream) {
    const float* x  = (const float*)d_in[0];
    const float* Wq = (const float*)d_in[1];
    const float* bq = (const float*)d_in[2];
    const float* Wk = (const float*)d_in[3];
    const float* bk = (const float*)d_in[4];
    const float* Wv = (const float*)d_in[5];
    const float* bv = (const float*)d_in[6];
    float* outp = (float*)d_out;

    const size_t ne  = (size_t)Bb * Ll * Ee;   // 4194304
    const size_t wne = (size_t)3 * Ee * Ee;    // 786432
    short* Qhi  = (short*)d_ws;
    short* Qlo  = Qhi + ne;
    short* Khi  = Qlo + ne;
    short* Klo  = Khi + ne;
    short* Vthi = Klo + ne;
    short* Vtlo = Vthi + ne;
    short* xsh  = Vtlo + ne;
    short* xsl  = xsh + ne;
    short* wth  = xsl + ne;
    short* wtl  = wth + wne;
    const size_t needed = (8 * ne + 2 * wne) * sizeof(short);   // 70.25 MB

    dim3 gemm_grid(Ee / 64, (Bb * Ll) / 64, 3);   // (8, 128, 3)
    if (ws_size >= needed) {
        split_x_kernel<<<(int)(ne / 8 / 256), 256, 0, stream>>>(x, xsh, xsl);
        split_w_kernel<<<dim3(8, 8, 3), 256, 0, stream>>>(Wq, Wk, Wv, wth, wtl);
        qkv_mfma_kernel<<<gemm_grid, 256, 0, stream>>>(xsh, xsl, wth, wtl,
                                                       bq, bk, bv,
                                                       Qhi, Qlo, Khi, Klo, Vthi, Vtlo);
    } else {
        qkv_gemm_kernel<<<gemm_grid, 256, 0, stream>>>(x, Wq, bq, Wk, bk, Wv, bv,
                                                       Qhi, Qlo, Khi, Klo, Vthi, Vtlo);
    }

    dim3 attn_grid(Ll / 128, NH, Bb);             // (16, 8, 4) = 512 blocks
    attn_kernel<<<attn_grid, 256, 0, stream>>>(Qhi, Qlo, Khi, Klo, Vthi, Vtlo, outp);
}